// Round 4
// baseline (2662.049 us; speedup 1.0000x reference)
//
#include <hip/hip_runtime.h>

// Problem constants
#define B_ 8
#define C_ 128
#define HW_ 512
#define PS 16
#define E_ 16
#define NP 1024   // patches per batch (32x32)
#define FD 512
#define CH_STRIDE (HW_ * HW_)   // x channel stride in floats

// d_out layout (flat f32):
// [0, 131072)        gates   [B, NP, E]
// [131072, 163840)   top_k_indices as float [B, NP, 4]
// [163840, 196608)   top_k_values [B, NP, 4]
// [196608]           aux_loss (0.0f)

__global__ void freq_kernel(const float* __restrict__ femb,
                            const float* __restrict__ fw,
                            float* __restrict__ freqf,
                            float* __restrict__ out) {
    int t = threadIdx.x;
    if (t == 0) out[196608] = 0.0f;  // aux_loss, rewritten every launch
    if (t < 128) {
        int b = t >> 4, e = t & 15;
        const float* fe = femb + b * FD;
        const float* w  = fw + e * FD;
        double s = 0.0;
        for (int i = 0; i < FD; ++i)
            s = fma((double)fe[i], (double)w[i], s);
        freqf[t] = (float)s;
    }
}

// Strict sequential f32 mul-then-add per (patch, expert) logit, np order
// (c outer, p, q innermost). Identical rounding to the round-3 kernel; only
// the load schedule changed: depth-3 register prefetch over the 2048 linear
// (c,p) rows, 4 rotating buffers (index p&3 is static after full unroll).
#define MAC4(XF, WF)                                        \
    acc = __fadd_rn(acc, __fmul_rn((XF).x, (WF).x));        \
    acc = __fadd_rn(acc, __fmul_rn((XF).y, (WF).y));        \
    acc = __fadd_rn(acc, __fmul_rn((XF).z, (WF).z));        \
    acc = __fadd_rn(acc, __fmul_rn((XF).w, (WF).w));

#define ROW_BODY(P, DOLOAD)                                                  \
  {                                                                          \
    const int LB = ((P) + 3) & 3;                                            \
    const int CB = (P) & 3;                                                  \
    if (DOLOAD) {                                                            \
      const float4* xr = reinterpret_cast<const float4*>(xpf);               \
      const float4* wr = reinterpret_cast<const float4*>(wpf);               \
      xq[LB][0] = xr[0]; xq[LB][1] = xr[1];                                  \
      xq[LB][2] = xr[2]; xq[LB][3] = xr[3];                                  \
      wq[LB][0] = wr[0]; wq[LB][1] = wr[1];                                  \
      wq[LB][2] = wr[2]; wq[LB][3] = wr[3];                                  \
    }                                                                        \
    xpf += ((P) == 12) ? (CH_STRIDE - 15 * HW_) : HW_;                       \
    wpf += 16;                                                               \
    MAC4(xq[CB][0], wq[CB][0]);                                              \
    MAC4(xq[CB][1], wq[CB][1]);                                              \
    MAC4(xq[CB][2], wq[CB][2]);                                              \
    MAC4(xq[CB][3], wq[CB][3]);                                              \
  }

__global__ __launch_bounds__(256) void patch_route_kernel(
    const float* __restrict__ x,
    const float* __restrict__ noise,
    const float* __restrict__ conv_w,
    const float* __restrict__ conv_b,
    const float* __restrict__ freqf,
    float* __restrict__ out) {

  const int blk = blockIdx.x;     // 0..511
  const int b   = blk >> 6;
  const int pg  = blk & 63;       // patch group of 16
  const int t   = threadIdx.x;
  const int lp  = t >> 4;         // local patch 0..15
  const int e   = t & 15;         // expert
  const int patch = pg * 16 + lp;        // 0..1023
  const int pi = patch >> 5, pj = patch & 31;

  const float* xb = x + (size_t)b * (C_ * CH_STRIDE)
                      + (size_t)(pi * PS) * HW_ + pj * PS;

  float4 xq[4][4], wq[4][4];
  const float* xpf = xb;                              // row (c=0,p=0)
  const float* wpf = conv_w + (size_t)e * 32768;      // row 0 of this expert

  // prologue: prefetch rows 0,1,2
  #pragma unroll
  for (int r = 0; r < 3; ++r) {
    const float4* xr = reinterpret_cast<const float4*>(xpf);
    const float4* wr = reinterpret_cast<const float4*>(wpf);
    xq[r][0] = xr[0]; xq[r][1] = xr[1]; xq[r][2] = xr[2]; xq[r][3] = xr[3];
    wq[r][0] = wr[0]; wq[r][1] = wr[1]; wq[r][2] = wr[2]; wq[r][3] = wr[3];
    xpf += HW_; wpf += 16;
  }

  float acc = 0.0f;
  for (int c = 0; c < 127; ++c) {
    #pragma unroll
    for (int p = 0; p < 16; ++p) ROW_BODY(p, true)
  }
  // peeled last channel: rows 2032..2047; prefetch only while target < 2048
  #pragma unroll
  for (int p = 0; p < 16; ++p) ROW_BODY(p, (p < 13))

  // logits, f32 adds in reference order: (+conv_b) -> (+freq) -> (+noise)
  float lg = __fadd_rn(acc, conv_b[e]);
  lg = __fadd_rn(lg, freqf[b * 16 + e]);
  lg = __fadd_rn(lg, noise[((size_t)b * NP + patch) * 16 + e]);

  __shared__ float slg[16][16];
  slg[lp][e] = lg;
  __syncthreads();

  // ---- f32 softmax + top-4, one thread per patch (identical to round 3) ----
  if (t < 16) {
    const int pp = t;
    const int pat = pg * 16 + pp;
    float v[16];
    #pragma unroll
    for (int i = 0; i < 16; ++i) v[i] = slg[pp][i];

    float m = v[0];
    #pragma unroll
    for (int i = 1; i < 16; ++i) m = fmaxf(m, v[i]);

    float ex[16];
    #pragma unroll
    for (int i = 0; i < 16; ++i) ex[i] = expf(v[i] - m);

    // numpy pairwise-16 sum for the denominator
    float r[8];
    #pragma unroll
    for (int j = 0; j < 8; ++j) r[j] = __fadd_rn(ex[j], ex[j + 8]);
    float d0 = __fadd_rn(__fadd_rn(r[0], r[1]), __fadd_rn(r[2], r[3]));
    float d1 = __fadd_rn(__fadd_rn(r[4], r[5]), __fadd_rn(r[6], r[7]));
    float den = __fadd_rn(d0, d1);

    float s[16];
    #pragma unroll
    for (int i = 0; i < 16; ++i) s[i] = ex[i] / den;

    unsigned mask = 0;
    int bidx[4]; float bval[4];
    #pragma unroll
    for (int j = 0; j < 4; ++j) {
      int bi = 0; float bv = -1.0f;
      #pragma unroll
      for (int i = 0; i < 16; ++i) {
        if (!((mask >> i) & 1u) && s[i] > bv) { bv = s[i]; bi = i; }
      }
      mask |= 1u << bi;
      bidx[j] = bi; bval[j] = bv;
    }

    const size_t po = (size_t)b * NP + pat;
    float* gout = out + po * 16;
    float* iout = out + 131072 + po * 4;
    float* vout = out + 163840 + po * 4;
    #pragma unroll
    for (int j = 0; j < 4; ++j) {
      iout[j] = (float)bidx[j];
      vout[j] = bval[j];
    }
    #pragma unroll
    for (int i = 0; i < 16; ++i)
      gout[i] = ((mask >> i) & 1u) ? s[i] : 0.0f;
  }
}

extern "C" void kernel_launch(void* const* d_in, const int* in_sizes, int n_in,
                              void* d_out, int out_size, void* d_ws, size_t ws_size,
                              hipStream_t stream) {
  const float* x     = (const float*)d_in[0];
  const float* femb  = (const float*)d_in[1];
  const float* noise = (const float*)d_in[2];
  const float* cw    = (const float*)d_in[3];
  const float* cb    = (const float*)d_in[4];
  const float* fw    = (const float*)d_in[5];
  float* out = (float*)d_out;
  float* freqf = (float*)d_ws;   // 128 floats

  hipLaunchKernelGGL(freq_kernel, dim3(1), dim3(128), 0, stream,
                     femb, fw, freqf, out);
  hipLaunchKernelGGL(patch_route_kernel, dim3(512), dim3(256), 0, stream,
                     x, noise, cw, cb, freqf, out);
}

// Round 5
// 360.388 us; speedup vs baseline: 7.3866x; 7.3866x over previous
//
#include <hip/hip_runtime.h>

// Problem constants
#define B_ 8
#define C_ 128
#define HW_ 512
#define PS 16
#define E_ 16
#define NP 1024   // patches per batch (32x32)
#define FD 512
#define CH_STRIDE (HW_ * HW_)   // x channel stride in floats

// d_out layout (flat f32):
// [0, 131072)        gates   [B, NP, E]
// [131072, 163840)   top_k_indices as float [B, NP, 4]
// [163840, 196608)   top_k_values [B, NP, 4]
// [196608]           aux_loss (0.0f)

__global__ void freq_kernel(const float* __restrict__ femb,
                            const float* __restrict__ fw,
                            float* __restrict__ freqf,
                            float* __restrict__ out) {
    int t = threadIdx.x;
    if (t == 0) out[196608] = 0.0f;  // aux_loss, rewritten every launch
    if (t < 128) {
        int b = t >> 4, e = t & 15;
        const float* fe = femb + b * FD;
        const float* w  = fw + e * FD;
        double s = 0.0;
        for (int i = 0; i < FD; ++i)
            s = fma((double)fe[i], (double)w[i], s);
        freqf[t] = (float)s;
    }
}

#define MAC4(XF, WF)                                        \
    acc = __fadd_rn(acc, __fmul_rn((XF).x, (WF).x));        \
    acc = __fadd_rn(acc, __fmul_rn((XF).y, (WF).y));        \
    acc = __fadd_rn(acc, __fmul_rn((XF).z, (WF).z));        \
    acc = __fadd_rn(acc, __fmul_rn((XF).w, (WF).w));

// direct global -> LDS, 16B per lane; LDS dest = uniform base + lane*16
#define GLOAD_LDS(GSRC, LDST)                                                  \
  __builtin_amdgcn_global_load_lds(                                            \
      (const __attribute__((address_space(1))) void*)(GSRC),                   \
      (__attribute__((address_space(3))) void*)(LDST), 16, 0, 0)

#define LROW 260   // padded LDS row (floats): stride%32==4 -> 2-way conflicts only

// Strict sequential f32 mul-then-add per (patch, expert) logit in np order
// (c outer, p, q innermost) -- rounding identical to the round-3 kernel.
// Memory restructured: per channel, x tile (16 rows x 1KB) and w tile
// (16 experts x 1KB) are staged global->LDS with global_load_lds into a
// double buffer; counted s_waitcnt vmcnt(8) + raw s_barrier keeps the next
// channel's 8 loads/wave in flight across the barrier.
__global__ __launch_bounds__(256, 2) void patch_route_kernel(
    const float* __restrict__ x,
    const float* __restrict__ noise,
    const float* __restrict__ conv_w,
    const float* __restrict__ conv_b,
    const float* __restrict__ freqf,
    float* __restrict__ out) {

  __shared__ float xs[2][16][LROW];   // [buf][pixel row p][256 cols + pad]
  __shared__ float ws[2][16][LROW];   // [buf][expert e][256 + pad]
  __shared__ float slg[16][16];

  const int blk = blockIdx.x;     // 0..511
  const int b   = blk >> 6;
  const int pg  = blk & 63;       // patch group of 16
  const int t   = threadIdx.x;
  const int lp  = t >> 4;         // local patch 0..15
  const int e   = t & 15;         // expert
  const int lp16 = lp * 16;
  const int patch = pg * 16 + lp;        // 0..1023
  const int pi = pg >> 1;                // patch row
  const int wv   = t >> 6;               // wave 0..3
  const int lane = t & 63;

  // block x base: batch b, channel 0, pixel row pi*16, col (pg&1)*256
  const float* xblk = x + (size_t)b * (C_ * CH_STRIDE)
                        + (size_t)(pi * PS) * HW_ + (pg & 1) * 256;

  // ---- stage channel 0 ----
  {
    const float* xc = xblk;                    // c = 0
    const float* wc = conv_w;                  // c = 0
    #pragma unroll
    for (int r = 0; r < 4; ++r) {
      const int p = wv * 4 + r;
      GLOAD_LDS(xc + p * HW_ + lane * 4, &xs[0][p][0]);
    }
    #pragma unroll
    for (int r = 0; r < 4; ++r) {
      const int ee = wv * 4 + r;
      GLOAD_LDS(wc + (size_t)ee * 32768 + lane * 4, &ws[0][ee][0]);
    }
  }

  float acc = 0.0f;
  for (int c = 0; c < C_; ++c) {
    const int cur = c & 1;
    if (c + 1 < C_) {
      // issue next channel's 8 loads/wave, then wait only for current's
      const int nb = cur ^ 1;
      const float* xc = xblk + (size_t)(c + 1) * CH_STRIDE;
      const float* wc = conv_w + (c + 1) * 256;
      #pragma unroll
      for (int r = 0; r < 4; ++r) {
        const int p = wv * 4 + r;
        GLOAD_LDS(xc + p * HW_ + lane * 4, &xs[nb][p][0]);
      }
      #pragma unroll
      for (int r = 0; r < 4; ++r) {
        const int ee = wv * 4 + r;
        GLOAD_LDS(wc + (size_t)ee * 32768 + lane * 4, &ws[nb][ee][0]);
      }
      asm volatile("s_waitcnt vmcnt(8)" ::: "memory");
    } else {
      asm volatile("s_waitcnt vmcnt(0)" ::: "memory");
    }
    __builtin_amdgcn_s_barrier();          // raw: no vmcnt(0) auto-drain
    __builtin_amdgcn_sched_barrier(0);

    // consume buffer `cur`: strict np-order chain (p outer, q inner)
    #pragma unroll
    for (int p = 0; p < 16; ++p) {
      const float4 x0 = *reinterpret_cast<const float4*>(&xs[cur][p][lp16 +  0]);
      const float4 x1 = *reinterpret_cast<const float4*>(&xs[cur][p][lp16 +  4]);
      const float4 x2 = *reinterpret_cast<const float4*>(&xs[cur][p][lp16 +  8]);
      const float4 x3 = *reinterpret_cast<const float4*>(&xs[cur][p][lp16 + 12]);
      const float4 w0 = *reinterpret_cast<const float4*>(&ws[cur][e][p * 16 +  0]);
      const float4 w1 = *reinterpret_cast<const float4*>(&ws[cur][e][p * 16 +  4]);
      const float4 w2 = *reinterpret_cast<const float4*>(&ws[cur][e][p * 16 +  8]);
      const float4 w3 = *reinterpret_cast<const float4*>(&ws[cur][e][p * 16 + 12]);
      MAC4(x0, w0);
      MAC4(x1, w1);
      MAC4(x2, w2);
      MAC4(x3, w3);
    }

    __builtin_amdgcn_sched_barrier(0);
    __builtin_amdgcn_s_barrier();          // all waves done with `cur`
  }

  // logits, f32 adds in reference order: (+conv_b) -> (+freq) -> (+noise)
  float lg = __fadd_rn(acc, conv_b[e]);
  lg = __fadd_rn(lg, freqf[b * 16 + e]);
  lg = __fadd_rn(lg, noise[((size_t)b * NP + patch) * 16 + e]);

  slg[lp][e] = lg;
  __syncthreads();

  // ---- f32 softmax + top-4, one thread per patch (identical to round 3) ----
  if (t < 16) {
    const int pp = t;
    const int pat = pg * 16 + pp;
    float v[16];
    #pragma unroll
    for (int i = 0; i < 16; ++i) v[i] = slg[pp][i];

    float m = v[0];
    #pragma unroll
    for (int i = 1; i < 16; ++i) m = fmaxf(m, v[i]);

    float ex[16];
    #pragma unroll
    for (int i = 0; i < 16; ++i) ex[i] = expf(v[i] - m);

    // numpy pairwise-16 sum for the denominator
    float r[8];
    #pragma unroll
    for (int j = 0; j < 8; ++j) r[j] = __fadd_rn(ex[j], ex[j + 8]);
    float d0 = __fadd_rn(__fadd_rn(r[0], r[1]), __fadd_rn(r[2], r[3]));
    float d1 = __fadd_rn(__fadd_rn(r[4], r[5]), __fadd_rn(r[6], r[7]));
    float den = __fadd_rn(d0, d1);

    float s[16];
    #pragma unroll
    for (int i = 0; i < 16; ++i) s[i] = ex[i] / den;

    unsigned mask = 0;
    int bidx[4]; float bval[4];
    #pragma unroll
    for (int j = 0; j < 4; ++j) {
      int bi = 0; float bv = -1.0f;
      #pragma unroll
      for (int i = 0; i < 16; ++i) {
        if (!((mask >> i) & 1u) && s[i] > bv) { bv = s[i]; bi = i; }
      }
      mask |= 1u << bi;
      bidx[j] = bi; bval[j] = bv;
    }

    const size_t po = (size_t)b * NP + pat;
    float* gout = out + po * 16;
    float* iout = out + 131072 + po * 4;
    float* vout = out + 163840 + po * 4;
    #pragma unroll
    for (int j = 0; j < 4; ++j) {
      iout[j] = (float)bidx[j];
      vout[j] = bval[j];
    }
    #pragma unroll
    for (int i = 0; i < 16; ++i)
      gout[i] = ((mask >> i) & 1u) ? s[i] : 0.0f;
  }
}

extern "C" void kernel_launch(void* const* d_in, const int* in_sizes, int n_in,
                              void* d_out, int out_size, void* d_ws, size_t ws_size,
                              hipStream_t stream) {
  const float* x     = (const float*)d_in[0];
  const float* femb  = (const float*)d_in[1];
  const float* noise = (const float*)d_in[2];
  const float* cw    = (const float*)d_in[3];
  const float* cb    = (const float*)d_in[4];
  const float* fw    = (const float*)d_in[5];
  float* out = (float*)d_out;
  float* freqf = (float*)d_ws;   // 128 floats

  hipLaunchKernelGGL(freq_kernel, dim3(1), dim3(128), 0, stream,
                     femb, fw, freqf, out);
  hipLaunchKernelGGL(patch_route_kernel, dim3(512), dim3(256), 0, stream,
                     x, noise, cw, cb, freqf, out);
}